// Round 18
// baseline (380.674 us; speedup 1.0000x reference)
//
#include <hip/hip_runtime.h>
#include <hip/hip_bf16.h>
#include <stdint.h>

#define B_   8
#define N_   8192
#define C_   512
#define NB   256   // blocks per sequence (N_/32)
#define WIN  64

typedef __attribute__((ext_vector_type(8))) short short8;
typedef __attribute__((ext_vector_type(4))) float f32x4;
typedef __hip_bfloat16 bf16;

__device__ __forceinline__ void gload_lds16(const void* g, void* l) {
  __builtin_amdgcn_global_load_lds((const __attribute__((address_space(1))) void*)g,
                                   (__attribute__((address_space(3))) void*)l, 16, 0, 0);
}

__device__ __forceinline__ f32x4 mfma16(short8 a, short8 b, f32x4 c) {
  return __builtin_amdgcn_mfma_f32_16x16x32_bf16(a, b, c, 0, 0, 0);
}

// ---------------- conversion kernels ----------------

__global__ __launch_bounds__(256) void k_conv_x(const float4* __restrict__ x,
                                                ushort4* __restrict__ xb) {
  size_t idx = (size_t)blockIdx.x * 256 + threadIdx.x;   // one float4 each
  float4 v = x[idx];
  union { ushort4 u; bf16 b[4]; } o;
  o.b[0] = __float2bfloat16(v.x); o.b[1] = __float2bfloat16(v.y);
  o.b[2] = __float2bfloat16(v.z); o.b[3] = __float2bfloat16(v.w);
  xb[idx] = o.u;
}

// Coalesced LDS tile-transpose: W (512 x ldw f32, row-major) -> Wt[o][k] bf16.
__global__ __launch_bounds__(256) void k_conv_w(const float* __restrict__ W,
                                                const float* __restrict__ bsrc,
                                                bf16* __restrict__ Wt,
                                                float* __restrict__ bperm,
                                                int ldw, int qkv) {
  __shared__ float tile[32][65];
  const int cc = blockIdx.x, k0 = blockIdx.y * 32;
  const int src0 = cc * 64;
  const int o0 = qkv ? ((cc % 3) * 512 + (cc / 3) * 64) : src0;
  const int tid = threadIdx.x;
#pragma unroll
  for (int q = 0; q < 8; ++q) {
    int li = q * 256 + tid;
    int r = li >> 6, c = li & 63;
    tile[r][c] = W[(size_t)(k0 + r) * ldw + src0 + c];
  }
  __syncthreads();
#pragma unroll
  for (int q = 0; q < 8; ++q) {
    int li = q * 256 + tid;
    int c2 = li >> 5, kk = li & 31;
    Wt[(size_t)(o0 + c2) * 512 + k0 + kk] = __float2bfloat16(tile[kk][c2]);
  }
  if (qkv && blockIdx.y == 0 && tid < 64) bperm[o0 + tid] = bsrc[src0 + tid];
}

// ---------------- GEMM: 256x256 tile, BK=64, B-IN-REGS pipelined -------------
// LDS-BW model: A+B-in-LDS carries 256KB/K-tile on the LDS pipe (~2290 cyc) vs
// 614 cyc MFMA -> 27-35% cap (measured r6-r15). Fix: B double-buffered in
// REGISTERS, loaded one K-tile AHEAD (B(t+1) issued at tile-t start; full tile
// of MFMA covers L2 latency — r16 failed because B was consumed same-phase).
// LDS now holds only A (2x32KB dbuf): 160KB/K-tile -> cap ~43%.
// One barrier/K-tile: [issue B(t+1) regs + stage A(t+1)] -> frag reads + 64
// MFMA -> vmcnt(0)+lgkm(0)+barrier (A(t+1) cooperative-DMA landed; buf-d reads
// done before t+1 overwrites it). Static B-reg indexing via unrolled pairs.
#define WAITV(N) asm volatile("s_waitcnt vmcnt(" #N ")" ::: "memory")

template <int EPI>
__global__ __launch_bounds__(512) void k_gemm(const bf16* __restrict__ A,
                                              const bf16* __restrict__ Bt,
                                              const float* __restrict__ bias,
                                              bf16* __restrict__ qb,
                                              bf16* __restrict__ kb,
                                              bf16* __restrict__ vb,
                                              float* __restrict__ outf,
                                              int NT) {
  extern __shared__ char gsm[];   // A dbuf: buf E at E*32768 (256 rows x 128B)
  const int tid = threadIdx.x;
  const int lane = tid & 63, wid = tid >> 6;
  const int wr = wid >> 2, wcn = wid & 3;
  const int l15 = lane & 15, l4 = lane >> 4;

  const int nwg = gridDim.x;
  const int cpx = nwg >> 3;
  const int swz = (blockIdx.x & 7) * cpx + (blockIdx.x >> 3);
  const int mt = swz / NT, nt = swz % NT;
  const size_t m0 = (size_t)mt * 256;
  const int n0 = nt * 256;

  f32x4 acc[8][4];
#pragma unroll
  for (int fi = 0; fi < 8; ++fi)
#pragma unroll
    for (int fj = 0; fj < 4; ++fj) acc[fi][fj] = (f32x4){0.f, 0.f, 0.f, 0.f};

  short8 bA[4][2], bB[4][2], af[4][2];

#define LOAD_B(DST, T)                                                         \
  { _Pragma("unroll") for (int f = 0; f < 4; ++f) {                            \
      const bf16* bp = Bt + (size_t)(n0 + f * 64 + wcn * 16 + l15) * 512 +     \
                       (T) * 64 + l4 * 8;                                      \
      DST[f][0] = *(const short8*)bp;                                          \
      DST[f][1] = *(const short8*)(bp + 32);                                   \
    } }

#define STAGE_A(E, K0)                                                         \
  { _Pragma("unroll") for (int q = 0; q < 4; ++q) {                            \
      int li = q * 512 + tid;                                                  \
      int r = li >> 3, g = (li & 7) ^ (r & 7);                                 \
      gload_lds16(A + (m0 + r) * 512 + (K0) + g * 8,                           \
                  gsm + (E) * 32768 + li * 16);                                \
    } }

  // one K-tile: compute with BCUR + buf(T&1); prefetch BNXT + buf((T&1)^1)
#define TILE_BODY(BCUR, BNXT, T, MORE)                                         \
  {                                                                            \
    if (MORE) {                                                                \
      LOAD_B(BNXT, (T) + 1);                                                   \
      STAGE_A(((T) & 1) ^ 1, ((T) + 1) * 64);                                  \
    }                                                                          \
    __builtin_amdgcn_sched_barrier(0);                                         \
    const char* Ab = gsm + ((T) & 1) * 32768;                                  \
    _Pragma("unroll") for (int f = 0; f < 4; ++f) {                            \
      int rA = f * 32 + wr * 16 + l15;                                         \
      af[f][0] = *(const short8*)(Ab + rA * 128 + ((l4 ^ (rA & 7)) << 4));     \
      af[f][1] = *(const short8*)(Ab + rA * 128 + (((4 + l4) ^ (rA & 7)) << 4));\
    }                                                                          \
    __builtin_amdgcn_s_setprio(1);                                             \
    _Pragma("unroll") for (int f = 0; f < 4; ++f)                              \
      _Pragma("unroll") for (int g = 0; g < 4; ++g) {                          \
        acc[f][g] = mfma16(af[f][0], BCUR[g][0], acc[f][g]);                   \
        acc[f][g] = mfma16(af[f][1], BCUR[g][1], acc[f][g]);                   \
      }                                                                        \
    __builtin_amdgcn_s_setprio(0);                                             \
    _Pragma("unroll") for (int f = 0; f < 4; ++f) {                            \
      int rA = 128 + f * 32 + wr * 16 + l15;                                   \
      af[f][0] = *(const short8*)(Ab + rA * 128 + ((l4 ^ (rA & 7)) << 4));     \
      af[f][1] = *(const short8*)(Ab + rA * 128 + (((4 + l4) ^ (rA & 7)) << 4));\
    }                                                                          \
    __builtin_amdgcn_s_setprio(1);                                             \
    _Pragma("unroll") for (int f = 0; f < 4; ++f)                              \
      _Pragma("unroll") for (int g = 0; g < 4; ++g) {                          \
        acc[4 + f][g] = mfma16(af[f][0], BCUR[g][0], acc[4 + f][g]);           \
        acc[4 + f][g] = mfma16(af[f][1], BCUR[g][1], acc[4 + f][g]);           \
      }                                                                        \
    __builtin_amdgcn_s_setprio(0);                                             \
    __builtin_amdgcn_sched_barrier(0);                                         \
    if (MORE) {                                                                \
      WAITV(0);                                                                \
      asm volatile("s_waitcnt lgkmcnt(0)" ::: "memory");                       \
      __builtin_amdgcn_s_barrier();                                            \
      __builtin_amdgcn_sched_barrier(0);                                       \
    }                                                                          \
  }

  // prologue: B(0) -> bA regs, A(0) -> buf 0
  LOAD_B(bA, 0);
  STAGE_A(0, 0);
  WAITV(0);
  __builtin_amdgcn_s_barrier();

  TILE_BODY(bA, bB, 0, true);
  TILE_BODY(bB, bA, 1, true);
  TILE_BODY(bA, bB, 2, true);
  TILE_BODY(bB, bA, 3, true);
  TILE_BODY(bA, bB, 4, true);
  TILE_BODY(bB, bA, 5, true);
  TILE_BODY(bA, bB, 6, true);
  TILE_BODY(bB, bA, 7, false);
#undef TILE_BODY
#undef STAGE_A
#undef LOAD_B

  if (EPI == 0) {
#pragma unroll
    for (int fi = 0; fi < 8; ++fi)
#pragma unroll
      for (int fj = 0; fj < 4; ++fj) {
        int o = n0 + fj * 64 + wcn * 16 + l15;
        float bia = bias[o];
        int part = o >> 9;
        int c = o & 511;
        bf16* dst = part == 0 ? qb : (part == 1 ? kb : vb);
#pragma unroll
        for (int r = 0; r < 4; ++r) {
          size_t m = m0 + fi * 32 + wr * 16 + l4 * 4 + r;
          int bidx = (int)(m >> 13);
          int n = (int)(m & 8191);
          int blk = n >> 5, s = n & 31;
          size_t di = (((size_t)(bidx * 32 + s) * 256 + blk) << 9) | c;
          dst[di] = __float2bfloat16(acc[fi][fj][r] + bia);
        }
      }
  } else {
#pragma unroll
    for (int fi = 0; fi < 8; ++fi)
#pragma unroll
      for (int fj = 0; fj < 4; ++fj) {
        int o = n0 + fj * 64 + wcn * 16 + l15;
        float bia = bias[o];
#pragma unroll
        for (int r = 0; r < 4; ++r) {
          size_t m = m0 + fi * 32 + wr * 16 + l4 * 4 + r;
          outf[m * 512 + o] = acc[fi][fj][r] + bia;
        }
      }
  }
}

// ---------------- v transpose: v[b][s][j][c] -> vT[b][s][c][j] ----------------
__global__ __launch_bounds__(256) void k_transpose_v(const bf16* __restrict__ v,
                                                     bf16* __restrict__ vT) {
  __shared__ bf16 t[32][36];
  int bs = blockIdx.x, j0 = blockIdx.y * 32, c0 = blockIdx.z * 32;
  const bf16* src = v + (size_t)bs * NB * C_;
  bf16* dst = vT + (size_t)bs * C_ * NB;
  int r = threadIdx.x >> 3, c4 = (threadIdx.x & 7) * 4;
  *(ushort4*)&t[r][c4] = *(const ushort4*)(src + (size_t)(j0 + r) * C_ + c0 + c4);
  __syncthreads();
  union { ushort4 u; bf16 b[4]; } o;
  o.b[0] = t[c4 + 0][r]; o.b[1] = t[c4 + 1][r];
  o.b[2] = t[c4 + 2][r]; o.b[3] = t[c4 + 3][r];
  *(ushort4*)(dst + (size_t)(c0 + r) * NB + j0 + c4) = o.u;
}

// ---------------- flash-style banded block attention (r12, proven best) ------
#define QS_OFF   0
#define KB_OFF   32768
#define VB_OFF   98304
#define SS_OFF   131072
#define PS_OFF   135296
#define SR_OFF   137856
#define MR_OFF   141952
#define LR_OFF   142080
#define AL_OFF   142208
#define ATTN_LDS 142336

__global__ __launch_bounds__(512) void k_attn(const bf16* __restrict__ qg,
                                              const bf16* __restrict__ kg,
                                              const bf16* __restrict__ vTg,
                                              bf16* __restrict__ outb) {
  extern __shared__ char smc[];
  float* Ssf  = (float*)(smc + SS_OFF);
  bf16*  Psb  = (bf16*)(smc + PS_OFF);
  float* Sred = (float*)(smc + SR_OFF);
  float* mrow = (float*)(smc + MR_OFF);
  float* lrow = (float*)(smc + LR_OFF);
  float* alph = (float*)(smc + AL_OFF);

  const int tid = threadIdx.x, lane = tid & 63, wid = tid >> 6;
  const int l15 = lane & 15, l4 = lane >> 4;
  const int gt = (blockIdx.x & 7) * 256 + (blockIdx.x >> 3);
  const int bs = gt >> 3;
  const int b = bs >> 5, s = bs & 31;
  const int i0 = (gt & 7) * 32;
  const int jlo = max(0, i0 - WIN);
  const int jhi = min(NB - 1, i0 + 31 + WIN);
  const int nch = (jhi - jlo + 1) >> 5;        // 3..5, band always 32-aligned
  const bf16* Qb = qg + (size_t)bs * NB * C_;
  const bf16* Kb = kg + (size_t)bs * NB * C_;
  const bf16* Vb = vTg + (size_t)bs * C_ * NB;

  const int qh_qk = (wid >> 2) & 1, jh = (wid >> 1) & 1, ks = wid & 1;
  const int qh_pv = wid >> 2, cq = wid & 3;

  f32x4 O[8];
#pragma unroll
  for (int f = 0; f < 8; ++f) O[f] = (f32x4){0.f, 0.f, 0.f, 0.f};

  if (tid < 32) { mrow[tid] = -1e30f; lrow[tid] = 0.f; }

#pragma unroll
  for (int q = 0; q < 4; ++q) {
    int li = q * 512 + tid;
    int row = li >> 6, g = (li & 63) ^ (row & 15);
    gload_lds16(Qb + (size_t)(i0 + row) * C_ + g * 8, smc + QS_OFF + li * 16);
  }
#pragma unroll
  for (int q = 0; q < 4; ++q) {
    int li = q * 512 + tid;
    int row = li >> 6, g = (li & 63) ^ (row & 15);
    gload_lds16(Kb + (size_t)(jlo + row) * C_ + g * 8, smc + KB_OFF + li * 16);
  }

  for (int t = 0; t < nch; ++t) {
    const int j0 = jlo + t * 32;
    asm volatile("s_waitcnt vmcnt(0) lgkmcnt(0)" ::: "memory");
    __builtin_amdgcn_s_barrier();
    __builtin_amdgcn_sched_barrier(0);

#pragma unroll
    for (int q = 0; q < 4; ++q) {
      int li = q * 512 + tid;
      int c = li >> 2, g = (li & 3) ^ (c & 3);
      gload_lds16(Vb + (size_t)c * NB + j0 + g * 8, smc + VB_OFF + li * 16);
    }
    if (t + 1 < nch) {
      int jn = j0 + 32;
      char* kdst = smc + KB_OFF + ((t + 1) & 1) * 32768;
#pragma unroll
      for (int q = 0; q < 4; ++q) {
        int li = q * 512 + tid;
        int row = li >> 6, g = (li & 63) ^ (row & 15);
        gload_lds16(Kb + (size_t)(jn + row) * C_ + g * 8, kdst + li * 16);
      }
    }

    {
      const int arow = qh_qk * 16 + l15;
      const int brow = jh * 16 + l15;
      const char* Qbase = smc + QS_OFF + arow * 1024;
      const char* Kbase = smc + KB_OFF + (t & 1) * 32768 + brow * 1024;
      f32x4 a0 = (f32x4){0.f, 0.f, 0.f, 0.f}, a1 = a0;
      __builtin_amdgcn_s_setprio(1);
#pragma unroll
      for (int cc = 0; cc < 8; ++cc) {
        int sa = (ks * 32 + cc * 4 + l4) ^ (arow & 15);
        int sb = (ks * 32 + cc * 4 + l4) ^ (brow & 15);
        short8 av = *(const short8*)(Qbase + sa * 16);
        short8 bv = *(const short8*)(Kbase + sb * 16);
        if (cc & 1) a1 = mfma16(av, bv, a1);
        else        a0 = mfma16(av, bv, a0);
      }
      __builtin_amdgcn_s_setprio(0);
      f32x4 acc = a0 + a1;
      if (ks) {
        *(f32x4*)&Sred[(wid >> 1) * 256 + lane * 4] = acc;
      }
      asm volatile("s_waitcnt lgkmcnt(0)" ::: "memory");
      __builtin_amdgcn_s_barrier();
      __builtin_amdgcn_sched_barrier(0);
      if (!ks) {
        f32x4 su = acc + *(f32x4*)&Sred[(wid >> 1) * 256 + lane * 4];
        int jg = j0 + jh * 16 + l15;
#pragma unroll
        for (int r = 0; r < 4; ++r) {
          int i_in = qh_qk * 16 + l4 * 4 + r;
          int i_abs = i0 + i_in;
          bool valid = (jg >= i_abs - WIN) && (jg <= i_abs + WIN);
          Ssf[i_in * 33 + jh * 16 + l15] = valid ? su[r] * 0.125f : -1e30f;
        }
      }
      asm volatile("s_waitcnt lgkmcnt(0)" ::: "memory");
      __builtin_amdgcn_s_barrier();
      __builtin_amdgcn_sched_barrier(0);
    }

    {
      int row = tid >> 4, u = tid & 15;
      float s0 = Ssf[row * 33 + u], s1 = Ssf[row * 33 + u + 16];
      float mc = fmaxf(s0, s1);
      mc = fmaxf(mc, __shfl_xor(mc, 1));
      mc = fmaxf(mc, __shfl_xor(mc, 2));
      mc = fmaxf(mc, __shfl_xor(mc, 4));
      mc = fmaxf(mc, __shfl_xor(mc, 8));
      float mo = mrow[row];
      float mn = fmaxf(mo, mc);
      float a = __expf(mo - mn);
      float p0 = __expf(s0 - mn), p1 = __expf(s1 - mn);
      float ps = p0 + p1;
      ps += __shfl_xor(ps, 1);
      ps += __shfl_xor(ps, 2);
      ps += __shfl_xor(ps, 4);
      ps += __shfl_xor(ps, 8);
      if (u == 0) {
        lrow[row] = lrow[row] * a + ps;
        mrow[row] = mn;
        alph[row] = a;
      }
      Psb[row * 40 + u] = __float2bfloat16(p0);
      Psb[row * 40 + u + 16] = __float2bfloat16(p1);
    }
    if (t + 1 < nch)
      asm volatile("s_waitcnt vmcnt(4) lgkmcnt(0)" ::: "memory");
    else
      asm volatile("s_waitcnt vmcnt(0) lgkmcnt(0)" ::: "memory");
    __builtin_amdgcn_s_barrier();
    __builtin_amdgcn_sched_barrier(0);

    {
      float ar[4];
#pragma unroll
      for (int r = 0; r < 4; ++r) ar[r] = alph[qh_pv * 16 + l4 * 4 + r];
      short8 pa = *(const short8*)(smc + PS_OFF + (qh_pv * 16 + l15) * 80 + l4 * 16);
      __builtin_amdgcn_s_setprio(1);
#pragma unroll
      for (int f = 0; f < 8; ++f) {
        int c = cq * 128 + f * 16 + l15;
        short8 vv = *(const short8*)(smc + VB_OFF + c * 64 + ((l4 ^ (c & 3)) << 4));
#pragma unroll
        for (int r = 0; r < 4; ++r) O[f][r] *= ar[r];
        O[f] = mfma16(pa, vv, O[f]);
      }
      __builtin_amdgcn_s_setprio(0);
    }
    __builtin_amdgcn_sched_barrier(0);
  }

  asm volatile("s_waitcnt lgkmcnt(0)" ::: "memory");
  __builtin_amdgcn_s_barrier();
  {
    float lr[4];
#pragma unroll
    for (int r = 0; r < 4; ++r) lr[r] = 1.f / lrow[qh_pv * 16 + l4 * 4 + r];
#pragma unroll
    for (int f = 0; f < 8; ++f) {
      int c = cq * 128 + f * 16 + l15;
#pragma unroll
      for (int r = 0; r < 4; ++r) {
        int il = qh_pv * 16 + l4 * 4 + r;
        int n = (i0 + il) * 32 + s;
        outb[((size_t)b * N_ + n) * C_ + c] = __float2bfloat16(O[f][r] * lr[r]);
      }
    }
  }
}

// ---------------- launch ----------------
extern "C" void kernel_launch(void* const* d_in, const int* in_sizes, int n_in,
                              void* d_out, int out_size, void* d_ws, size_t ws_size,
                              hipStream_t stream) {
  const float* x = (const float*)d_in[0];
  const float* Wqkv = (const float*)d_in[1];
  const float* bqkv = (const float*)d_in[2];
  const float* Wproj = (const float*)d_in[3];
  const float* bproj = (const float*)d_in[4];

  char* ws = (char*)d_ws;
  const size_t SLOT = 67108864ull;           // 64 MiB (33.5M bf16)
  bf16* slotA = (bf16*)ws;                   // xb, then vT
  bf16* slotB = (bf16*)(ws + SLOT);          // v, then attn_out
  bf16* Wqkv_t = (bf16*)(ws + 2 * SLOT);
  bf16* Wproj_t = (bf16*)(ws + 2 * SLOT + 1572864);
  float* bias_perm = (float*)(ws + 2 * SLOT + 1572864 + 524288);
  bf16* qbuf = (bf16*)d_out;                 // q,k scratch inside d_out (dead before proj writes)
  bf16* kbuf = qbuf + 33554432ull;

  static int attr_done = 0;
  if (!attr_done) {
    hipFuncSetAttribute((const void*)k_gemm<0>,
                        hipFuncAttributeMaxDynamicSharedMemorySize, 65536);
    hipFuncSetAttribute((const void*)k_gemm<1>,
                        hipFuncAttributeMaxDynamicSharedMemorySize, 65536);
    hipFuncSetAttribute((const void*)k_attn,
                        hipFuncAttributeMaxDynamicSharedMemorySize, ATTN_LDS);
    attr_done = 1;
  }

  k_conv_x<<<32768, 256, 0, stream>>>((const float4*)x, (ushort4*)slotA);
  k_conv_w<<<dim3(24, 16), 256, 0, stream>>>(Wqkv, bqkv, Wqkv_t, bias_perm, 1536, 1);
  k_conv_w<<<dim3(8, 16), 256, 0, stream>>>(Wproj, nullptr, Wproj_t, nullptr, 512, 0);

  // qkv projection: A=xb, Bt=Wqkv_t -> q,k (d_out), v (slotB)
  k_gemm<0><<<1536, 512, 65536, stream>>>(slotA, Wqkv_t, bias_perm,
                                          qbuf, kbuf, slotB, nullptr, 6);
  // v -> vT (slotA; xb dead)
  k_transpose_v<<<dim3(256, 8, 16), 256, 0, stream>>>(slotB, slotA);
  // attention -> attn_out (slotB; v dead)
  k_attn<<<2048, 512, ATTN_LDS, stream>>>(qbuf, kbuf, slotA, slotB);
  // proj: A=attn_out (slotB), Bt=Wproj_t -> d_out f32 (q,k dead)
  k_gemm<1><<<512, 512, 65536, stream>>>(slotB, Wproj_t, bproj,
                                         nullptr, nullptr, nullptr, (float*)d_out, 2);
}

// Round 19
// 327.656 us; speedup vs baseline: 1.1618x; 1.1618x over previous
//
#include <hip/hip_runtime.h>
#include <hip/hip_bf16.h>
#include <stdint.h>

#define B_   8
#define N_   8192
#define C_   512
#define NB   256   // blocks per sequence (N_/32)
#define WIN  64

typedef __attribute__((ext_vector_type(8))) short short8;
typedef __attribute__((ext_vector_type(4))) float f32x4;
typedef __hip_bfloat16 bf16;

__device__ __forceinline__ void gload_lds16(const void* g, void* l) {
  __builtin_amdgcn_global_load_lds((const __attribute__((address_space(1))) void*)g,
                                   (__attribute__((address_space(3))) void*)l, 16, 0, 0);
}

__device__ __forceinline__ f32x4 mfma16(short8 a, short8 b, f32x4 c) {
  return __builtin_amdgcn_mfma_f32_16x16x32_bf16(a, b, c, 0, 0, 0);
}

// ---------------- conversion kernels ----------------

__global__ __launch_bounds__(256) void k_conv_x(const float4* __restrict__ x,
                                                ushort4* __restrict__ xb) {
  size_t idx = (size_t)blockIdx.x * 256 + threadIdx.x;   // one float4 each
  float4 v = x[idx];
  union { ushort4 u; bf16 b[4]; } o;
  o.b[0] = __float2bfloat16(v.x); o.b[1] = __float2bfloat16(v.y);
  o.b[2] = __float2bfloat16(v.z); o.b[3] = __float2bfloat16(v.w);
  xb[idx] = o.u;
}

// Coalesced LDS tile-transpose: W (512 x ldw f32, row-major) -> Wt[o][k] bf16.
// qkv=1 applies the head-interleave column permutation in 64-wide chunks.
__global__ __launch_bounds__(256) void k_conv_w(const float* __restrict__ W,
                                                const float* __restrict__ bsrc,
                                                bf16* __restrict__ Wt,
                                                float* __restrict__ bperm,
                                                int ldw, int qkv) {
  __shared__ float tile[32][65];
  const int cc = blockIdx.x, k0 = blockIdx.y * 32;
  const int src0 = cc * 64;
  const int o0 = qkv ? ((cc % 3) * 512 + (cc / 3) * 64) : src0;
  const int tid = threadIdx.x;
#pragma unroll
  for (int q = 0; q < 8; ++q) {
    int li = q * 256 + tid;
    int r = li >> 6, c = li & 63;
    tile[r][c] = W[(size_t)(k0 + r) * ldw + src0 + c];
  }
  __syncthreads();
#pragma unroll
  for (int q = 0; q < 8; ++q) {
    int li = q * 256 + tid;
    int c2 = li >> 5, kk = li & 31;
    Wt[(size_t)(o0 + c2) * 512 + k0 + kk] = __float2bfloat16(tile[kk][c2]);
  }
  if (qkv && blockIdx.y == 0 && tid < 64) bperm[o0 + tid] = bsrc[src0 + tid];
}

// ---------------- GEMM: 256x256 tile, BK=64, 8-phase schedule (r12, best) -----
#define WAITV(N) asm volatile("s_waitcnt vmcnt(" #N ")" ::: "memory")

template <int EPI>
__global__ __launch_bounds__(512, 2) void k_gemm(const bf16* __restrict__ A,
                                                 const bf16* __restrict__ Bt,
                                                 const float* __restrict__ bias,
                                                 bf16* __restrict__ qb,
                                                 bf16* __restrict__ kb,
                                                 bf16* __restrict__ vb,
                                                 float* __restrict__ outf,
                                                 int NT) {
  extern __shared__ char gsm[];
  const int tid = threadIdx.x;
  const int lane = tid & 63, wid = tid >> 6;
  const int wr = wid >> 2, wcn = wid & 3;
  const int l15 = lane & 15, l4 = lane >> 4;
  const int sx = l15 & 7;

  const int nwg = gridDim.x;
  const int cpx = nwg >> 3;
  const int swz = (blockIdx.x & 7) * cpx + (blockIdx.x >> 3);
  const int mt = swz / NT, nt = swz % NT;
  const size_t m0 = (size_t)mt * 256;
  const int n0 = nt * 256;

  f32x4 acc[8][4];
#pragma unroll
  for (int fi = 0; fi < 8; ++fi)
#pragma unroll
    for (int fj = 0; fj < 4; ++fj) acc[fi][fj] = (f32x4){0.f, 0.f, 0.f, 0.f};

#define STAGE_A(E, H, K0)                                                      \
  { _Pragma("unroll") for (int q = 0; q < 2; ++q) {                            \
      int li = q * 512 + tid;                                                  \
      int r = li >> 3, g = (li & 7) ^ (r & 7);                                 \
      gload_lds16(A + (m0 + (H) * 128 + r) * 512 + (K0) + g * 8,               \
                  gsm + (E) * 65536 + (H) * 16384 + li * 16);                  \
    } }
#define STAGE_B(E, H, K0)                                                      \
  { _Pragma("unroll") for (int q = 0; q < 2; ++q) {                            \
      int li = q * 512 + tid;                                                  \
      int r = li >> 3, g = (li & 7) ^ (r & 7);                                 \
      gload_lds16(Bt + (size_t)(n0 + (H) * 128 + r) * 512 + (K0) + g * 8,      \
                  gsm + (E) * 65536 + 32768 + (H) * 16384 + li * 16);          \
    } }

#define PHASE(FIH, FJH, LOADA, STAGE_STMT, WAIT_STMT)                          \
  {                                                                            \
    const char* Ab = gsm + d * 65536 + (FIH) * 16384;                          \
    const char* Bb = gsm + d * 65536 + 32768 + (FJH) * 16384;                  \
    if (LOADA) {                                                               \
      _Pragma("unroll") for (int f = 0; f < 4; ++f) {                          \
        int rA = f * 32 + wr * 16 + l15;                                       \
        af[f][0] = *(const short8*)(Ab + rA * 128 + ((l4 ^ sx) << 4));         \
        af[f][1] = *(const short8*)(Ab + rA * 128 + (((4 + l4) ^ sx) << 4));   \
      }                                                                        \
    }                                                                          \
    _Pragma("unroll") for (int f = 0; f < 2; ++f) {                            \
      int rB = f * 64 + wcn * 16 + l15;                                        \
      bfr[f][0] = *(const short8*)(Bb + rB * 128 + ((l4 ^ sx) << 4));          \
      bfr[f][1] = *(const short8*)(Bb + rB * 128 + (((4 + l4) ^ sx) << 4));    \
    }                                                                          \
    STAGE_STMT;                                                                \
    __builtin_amdgcn_sched_barrier(0);                                         \
    __builtin_amdgcn_s_barrier();                                              \
    __builtin_amdgcn_sched_barrier(0);                                         \
    __builtin_amdgcn_s_setprio(1);                                             \
    _Pragma("unroll") for (int f = 0; f < 4; ++f)                              \
      _Pragma("unroll") for (int g = 0; g < 2; ++g) {                          \
        acc[(FIH) * 4 + f][(FJH) * 2 + g] =                                    \
            mfma16(af[f][0], bfr[g][0], acc[(FIH) * 4 + f][(FJH) * 2 + g]);    \
        acc[(FIH) * 4 + f][(FJH) * 2 + g] =                                    \
            mfma16(af[f][1], bfr[g][1], acc[(FIH) * 4 + f][(FJH) * 2 + g]);    \
      }                                                                        \
    __builtin_amdgcn_s_setprio(0);                                             \
    __builtin_amdgcn_sched_barrier(0);                                         \
    WAIT_STMT;                                                                 \
    __builtin_amdgcn_s_barrier();                                              \
  }

  // prologue: tile 0 (order A0,B0,B1,A1); vmcnt(4) -> A0,B0 landed
  STAGE_A(0, 0, 0); STAGE_B(0, 0, 0); STAGE_B(0, 1, 0); STAGE_A(0, 1, 0);
  WAITV(4);
  __builtin_amdgcn_s_barrier();

  short8 af[4][2], bfr[2][2];
  for (int t = 0; t < 8; ++t) {
    const int d = t & 1, e = d ^ 1;
    const int kn = (t + 1) * 64;
    PHASE(0, 0, 1,
          { if (t < 7) STAGE_A(e, 0, kn); },
          { if (t < 7) { WAITV(4); } else { WAITV(2); } });
    PHASE(0, 1, 0,
          { if (t < 7) STAGE_B(e, 0, kn); },
          { if (t < 7) { WAITV(4); } else { WAITV(0); } });
    PHASE(1, 0, 1,
          { if (t < 7) STAGE_B(e, 1, kn); },
          { });
    PHASE(1, 1, 0,
          { if (t < 7) STAGE_A(e, 1, kn); },
          { if (t < 7) { WAITV(4); } });
  }
#undef PHASE
#undef STAGE_A
#undef STAGE_B

  if (EPI == 0) {
#pragma unroll
    for (int fi = 0; fi < 8; ++fi)
#pragma unroll
      for (int fj = 0; fj < 4; ++fj) {
        int o = n0 + fj * 64 + wcn * 16 + l15;
        float bia = bias[o];
        int part = o >> 9;
        int c = o & 511;
        bf16* dst = part == 0 ? qb : (part == 1 ? kb : vb);
#pragma unroll
        for (int r = 0; r < 4; ++r) {
          size_t m = m0 + fi * 32 + wr * 16 + l4 * 4 + r;
          int bidx = (int)(m >> 13);
          int n = (int)(m & 8191);
          int blk = n >> 5, s = n & 31;
          size_t di = (((size_t)(bidx * 32 + s) * 256 + blk) << 9) | c;
          dst[di] = __float2bfloat16(acc[fi][fj][r] + bia);
        }
      }
  } else {
#pragma unroll
    for (int fi = 0; fi < 8; ++fi)
#pragma unroll
      for (int fj = 0; fj < 4; ++fj) {
        int o = n0 + fj * 64 + wcn * 16 + l15;
        float bia = bias[o];
#pragma unroll
        for (int r = 0; r < 4; ++r) {
          size_t m = m0 + fi * 32 + wr * 16 + l4 * 4 + r;
          outf[m * 512 + o] = acc[fi][fj][r] + bia;
        }
      }
  }
}

// ---------------- v transpose: v[b][s][j][c] -> vT[b][s][c][j] ----------------
__global__ __launch_bounds__(256) void k_transpose_v(const bf16* __restrict__ v,
                                                     bf16* __restrict__ vT) {
  __shared__ bf16 t[32][36];
  int bs = blockIdx.x, j0 = blockIdx.y * 32, c0 = blockIdx.z * 32;
  const bf16* src = v + (size_t)bs * NB * C_;
  bf16* dst = vT + (size_t)bs * C_ * NB;
  int r = threadIdx.x >> 3, c4 = (threadIdx.x & 7) * 4;
  *(ushort4*)&t[r][c4] = *(const ushort4*)(src + (size_t)(j0 + r) * C_ + c0 + c4);
  __syncthreads();
  union { ushort4 u; bf16 b[4]; } o;
  o.b[0] = t[c4 + 0][r]; o.b[1] = t[c4 + 1][r];
  o.b[2] = t[c4 + 2][r]; o.b[3] = t[c4 + 3][r];
  *(ushort4*)(dst + (size_t)(c0 + r) * NB + j0 + c4) = o.u;
}

// ---------------- flash-style banded block attention (r12, proven best) ------
#define QS_OFF   0
#define KB_OFF   32768
#define VB_OFF   98304
#define SS_OFF   131072
#define PS_OFF   135296
#define SR_OFF   137856
#define MR_OFF   141952
#define LR_OFF   142080
#define AL_OFF   142208
#define ATTN_LDS 142336

__global__ __launch_bounds__(512) void k_attn(const bf16* __restrict__ qg,
                                              const bf16* __restrict__ kg,
                                              const bf16* __restrict__ vTg,
                                              bf16* __restrict__ outb) {
  extern __shared__ char smc[];
  float* Ssf  = (float*)(smc + SS_OFF);
  bf16*  Psb  = (bf16*)(smc + PS_OFF);
  float* Sred = (float*)(smc + SR_OFF);
  float* mrow = (float*)(smc + MR_OFF);
  float* lrow = (float*)(smc + LR_OFF);
  float* alph = (float*)(smc + AL_OFF);

  const int tid = threadIdx.x, lane = tid & 63, wid = tid >> 6;
  const int l15 = lane & 15, l4 = lane >> 4;
  const int gt = (blockIdx.x & 7) * 256 + (blockIdx.x >> 3);
  const int bs = gt >> 3;
  const int b = bs >> 5, s = bs & 31;
  const int i0 = (gt & 7) * 32;
  const int jlo = max(0, i0 - WIN);
  const int jhi = min(NB - 1, i0 + 31 + WIN);
  const int nch = (jhi - jlo + 1) >> 5;        // 3..5, band always 32-aligned
  const bf16* Qb = qg + (size_t)bs * NB * C_;
  const bf16* Kb = kg + (size_t)bs * NB * C_;
  const bf16* Vb = vTg + (size_t)bs * C_ * NB;

  const int qh_qk = (wid >> 2) & 1, jh = (wid >> 1) & 1, ks = wid & 1;
  const int qh_pv = wid >> 2, cq = wid & 3;

  f32x4 O[8];
#pragma unroll
  for (int f = 0; f < 8; ++f) O[f] = (f32x4){0.f, 0.f, 0.f, 0.f};

  if (tid < 32) { mrow[tid] = -1e30f; lrow[tid] = 0.f; }

#pragma unroll
  for (int q = 0; q < 4; ++q) {
    int li = q * 512 + tid;
    int row = li >> 6, g = (li & 63) ^ (row & 15);
    gload_lds16(Qb + (size_t)(i0 + row) * C_ + g * 8, smc + QS_OFF + li * 16);
  }
#pragma unroll
  for (int q = 0; q < 4; ++q) {
    int li = q * 512 + tid;
    int row = li >> 6, g = (li & 63) ^ (row & 15);
    gload_lds16(Kb + (size_t)(jlo + row) * C_ + g * 8, smc + KB_OFF + li * 16);
  }

  for (int t = 0; t < nch; ++t) {
    const int j0 = jlo + t * 32;
    asm volatile("s_waitcnt vmcnt(0) lgkmcnt(0)" ::: "memory");
    __builtin_amdgcn_s_barrier();
    __builtin_amdgcn_sched_barrier(0);

#pragma unroll
    for (int q = 0; q < 4; ++q) {
      int li = q * 512 + tid;
      int c = li >> 2, g = (li & 3) ^ (c & 3);
      gload_lds16(Vb + (size_t)c * NB + j0 + g * 8, smc + VB_OFF + li * 16);
    }
    if (t + 1 < nch) {
      int jn = j0 + 32;
      char* kdst = smc + KB_OFF + ((t + 1) & 1) * 32768;
#pragma unroll
      for (int q = 0; q < 4; ++q) {
        int li = q * 512 + tid;
        int row = li >> 6, g = (li & 63) ^ (row & 15);
        gload_lds16(Kb + (size_t)(jn + row) * C_ + g * 8, kdst + li * 16);
      }
    }

    {
      const int arow = qh_qk * 16 + l15;
      const int brow = jh * 16 + l15;
      const char* Qbase = smc + QS_OFF + arow * 1024;
      const char* Kbase = smc + KB_OFF + (t & 1) * 32768 + brow * 1024;
      f32x4 a0 = (f32x4){0.f, 0.f, 0.f, 0.f}, a1 = a0;
      __builtin_amdgcn_s_setprio(1);
#pragma unroll
      for (int cc = 0; cc < 8; ++cc) {
        int sa = (ks * 32 + cc * 4 + l4) ^ (arow & 15);
        int sb = (ks * 32 + cc * 4 + l4) ^ (brow & 15);
        short8 av = *(const short8*)(Qbase + sa * 16);
        short8 bv = *(const short8*)(Kbase + sb * 16);
        if (cc & 1) a1 = mfma16(av, bv, a1);
        else        a0 = mfma16(av, bv, a0);
      }
      __builtin_amdgcn_s_setprio(0);
      f32x4 acc = a0 + a1;
      if (ks) {
        *(f32x4*)&Sred[(wid >> 1) * 256 + lane * 4] = acc;
      }
      asm volatile("s_waitcnt lgkmcnt(0)" ::: "memory");
      __builtin_amdgcn_s_barrier();
      __builtin_amdgcn_sched_barrier(0);
      if (!ks) {
        f32x4 su = acc + *(f32x4*)&Sred[(wid >> 1) * 256 + lane * 4];
        int jg = j0 + jh * 16 + l15;
#pragma unroll
        for (int r = 0; r < 4; ++r) {
          int i_in = qh_qk * 16 + l4 * 4 + r;
          int i_abs = i0 + i_in;
          bool valid = (jg >= i_abs - WIN) && (jg <= i_abs + WIN);
          Ssf[i_in * 33 + jh * 16 + l15] = valid ? su[r] * 0.125f : -1e30f;
        }
      }
      asm volatile("s_waitcnt lgkmcnt(0)" ::: "memory");
      __builtin_amdgcn_s_barrier();
      __builtin_amdgcn_sched_barrier(0);
    }

    {
      int row = tid >> 4, u = tid & 15;
      float s0 = Ssf[row * 33 + u], s1 = Ssf[row * 33 + u + 16];
      float mc = fmaxf(s0, s1);
      mc = fmaxf(mc, __shfl_xor(mc, 1));
      mc = fmaxf(mc, __shfl_xor(mc, 2));
      mc = fmaxf(mc, __shfl_xor(mc, 4));
      mc = fmaxf(mc, __shfl_xor(mc, 8));
      float mo = mrow[row];
      float mn = fmaxf(mo, mc);
      float a = __expf(mo - mn);
      float p0 = __expf(s0 - mn), p1 = __expf(s1 - mn);
      float ps = p0 + p1;
      ps += __shfl_xor(ps, 1);
      ps += __shfl_xor(ps, 2);
      ps += __shfl_xor(ps, 4);
      ps += __shfl_xor(ps, 8);
      if (u == 0) {
        lrow[row] = lrow[row] * a + ps;
        mrow[row] = mn;
        alph[row] = a;
      }
      Psb[row * 40 + u] = __float2bfloat16(p0);
      Psb[row * 40 + u + 16] = __float2bfloat16(p1);
    }
    if (t + 1 < nch)
      asm volatile("s_waitcnt vmcnt(4) lgkmcnt(0)" ::: "memory");
    else
      asm volatile("s_waitcnt vmcnt(0) lgkmcnt(0)" ::: "memory");
    __builtin_amdgcn_s_barrier();
    __builtin_amdgcn_sched_barrier(0);

    {
      float ar[4];
#pragma unroll
      for (int r = 0; r < 4; ++r) ar[r] = alph[qh_pv * 16 + l4 * 4 + r];
      short8 pa = *(const short8*)(smc + PS_OFF + (qh_pv * 16 + l15) * 80 + l4 * 16);
      __builtin_amdgcn_s_setprio(1);
#pragma unroll
      for (int f = 0; f < 8; ++f) {
        int c = cq * 128 + f * 16 + l15;
        short8 vv = *(const short8*)(smc + VB_OFF + c * 64 + ((l4 ^ (c & 3)) << 4));
#pragma unroll
        for (int r = 0; r < 4; ++r) O[f][r] *= ar[r];
        O[f] = mfma16(pa, vv, O[f]);
      }
      __builtin_amdgcn_s_setprio(0);
    }
    __builtin_amdgcn_sched_barrier(0);
  }

  asm volatile("s_waitcnt lgkmcnt(0)" ::: "memory");
  __builtin_amdgcn_s_barrier();
  {
    float lr[4];
#pragma unroll
    for (int r = 0; r < 4; ++r) lr[r] = 1.f / lrow[qh_pv * 16 + l4 * 4 + r];
#pragma unroll
    for (int f = 0; f < 8; ++f) {
      int c = cq * 128 + f * 16 + l15;
#pragma unroll
      for (int r = 0; r < 4; ++r) {
        int il = qh_pv * 16 + l4 * 4 + r;
        int n = (i0 + il) * 32 + s;
        outb[((size_t)b * N_ + n) * C_ + c] = __float2bfloat16(O[f][r] * lr[r]);
      }
    }
  }
}

// ---------------- launch ----------------
extern "C" void kernel_launch(void* const* d_in, const int* in_sizes, int n_in,
                              void* d_out, int out_size, void* d_ws, size_t ws_size,
                              hipStream_t stream) {
  const float* x = (const float*)d_in[0];
  const float* Wqkv = (const float*)d_in[1];
  const float* bqkv = (const float*)d_in[2];
  const float* Wproj = (const float*)d_in[3];
  const float* bproj = (const float*)d_in[4];

  char* ws = (char*)d_ws;
  const size_t SLOT = 67108864ull;           // 64 MiB (33.5M bf16)
  bf16* slotA = (bf16*)ws;                   // xb, then vT
  bf16* slotB = (bf16*)(ws + SLOT);          // v, then attn_out
  bf16* Wqkv_t = (bf16*)(ws + 2 * SLOT);
  bf16* Wproj_t = (bf16*)(ws + 2 * SLOT + 1572864);
  float* bias_perm = (float*)(ws + 2 * SLOT + 1572864 + 524288);
  bf16* qbuf = (bf16*)d_out;                 // q,k scratch inside d_out (dead before proj writes)
  bf16* kbuf = qbuf + 33554432ull;

  static int attr_done = 0;
  if (!attr_done) {
    hipFuncSetAttribute((const void*)k_gemm<0>,
                        hipFuncAttributeMaxDynamicSharedMemorySize, 131072);
    hipFuncSetAttribute((const void*)k_gemm<1>,
                        hipFuncAttributeMaxDynamicSharedMemorySize, 131072);
    hipFuncSetAttribute((const void*)k_attn,
                        hipFuncAttributeMaxDynamicSharedMemorySize, ATTN_LDS);
    attr_done = 1;
  }

  k_conv_x<<<32768, 256, 0, stream>>>((const float4*)x, (ushort4*)slotA);
  k_conv_w<<<dim3(24, 16), 256, 0, stream>>>(Wqkv, bqkv, Wqkv_t, bias_perm, 1536, 1);
  k_conv_w<<<dim3(8, 16), 256, 0, stream>>>(Wproj, nullptr, Wproj_t, nullptr, 512, 0);

  // qkv projection: A=xb, Bt=Wqkv_t -> q,k (d_out), v (slotB)
  k_gemm<0><<<1536, 512, 131072, stream>>>(slotA, Wqkv_t, bias_perm,
                                           qbuf, kbuf, slotB, nullptr, 6);
  // v -> vT (slotA; xb dead)
  k_transpose_v<<<dim3(256, 8, 16), 256, 0, stream>>>(slotB, slotA);
  // attention -> attn_out (slotB; v dead)
  k_attn<<<2048, 512, ATTN_LDS, stream>>>(qbuf, kbuf, slotA, slotB);
  // proj: A=attn_out (slotB), Bt=Wproj_t -> d_out f32 (q,k dead)
  k_gemm<1><<<512, 512, 131072, stream>>>(slotB, Wproj_t, bproj,
                                          nullptr, nullptr, nullptr, (float*)d_out, 2);
}